// Round 7
// baseline (230.912 us; speedup 1.0000x reference)
//
#include <hip/hip_runtime.h>
#include <math.h>
#include <stdint.h>

// tgate_hybrid: B=4,S=4096,DIMS=2048,T=10,K=2.
// R7 = R5 arithmetic BIT-FOR-BIT (rne-hi split-bf16, KSL=8, same MFMA order;
// R5 passed at absmax 0.0039 deterministically — R6's trunc-hi changed the
// rounding path and flipped a top-2 near-tie row) + ONE scheduling change:
// all 16 A-loads hoisted into a pre-loop batch (Little's law: 16 outstanding
// dwordx4/wave instead of ~4 -> x streams near HBM rate).
// k0: pack W hi/lo B-fragments. k1: MFMA partial GEMM. k2: reduce+epilogue.

#define NROWS   16384
#define DIMS_   2048
#define TT      10
#define NCOL    32
#define KSL     8                 // k-slices (R5 value)
#define KSTEPS  (DIMS_ / 32)      // 64 MFMA k-steps total
#define KPS     (KSTEPS / KSL)    // 8 k-steps per slice

typedef __attribute__((ext_vector_type(8))) short short8;
typedef __attribute__((ext_vector_type(4))) float f32x4;

__device__ __forceinline__ unsigned short bf16_rne(float f) {
    unsigned int u = __float_as_uint(f);
    unsigned int r = u + 0x7fffu + ((u >> 16) & 1u);
    return (unsigned short)(r >> 16);
}

// ---- k0: build B fragments. frag[(K0*4 + nt*2 + h)*64 + lane] = short8
//      B-frag layout (16x16x32): n = lane&15, k = (lane>>4)*8 + j.
__global__ __launch_bounds__(256)
void tgate_k0(const float* __restrict__ W_cls,
              const float* __restrict__ W_sparse,
              const float* __restrict__ W_gates,
              unsigned short* __restrict__ frag)
{
    int t = blockIdx.x * 256 + threadIdx.x;    // 8192 threads: (K0, nt, lane)
    int K0   = t >> 7;
    int nt   = (t >> 6) & 1;
    int lane = t & 63;
    int n  = nt * 16 + (lane & 15);
    int kb = K0 * 32 + (lane >> 4) * 8;
    short8 hi, lo;
    #pragma unroll
    for (int j = 0; j < 8; ++j) {
        int k = kb + j;
        float w = 0.0f;
        if (n < 10)      w = W_cls[k * TT + n];
        else if (n < 20) w = W_sparse[k * TT + n - 10];
        else if (n < 30) w = W_gates[k * TT + n - 20];
        unsigned short h = bf16_rne(w);
        float back = __uint_as_float(((unsigned int)h) << 16);
        hi[j] = (short)h;
        lo[j] = (short)bf16_rne(w - back);
    }
    short8* fv = reinterpret_cast<short8*>(frag);
    fv[(K0 * 4 + nt * 2 + 0) * 64 + lane] = hi;
    fv[(K0 * 4 + nt * 2 + 1) * 64 + lane] = lo;
}

// ---- k1: MFMA partial GEMM; R5 arithmetic, A-loads batched upfront
__global__ __launch_bounds__(256)
void tgate_k1(const float* __restrict__ x,
              const unsigned short* __restrict__ frag,
              float* __restrict__ part)
{
    const int lane  = threadIdx.x & 63;
    const int wv    = threadIdx.x >> 6;
    const int row0  = (blockIdx.x * 4 + wv) * 16;
    const int slice = blockIdx.y;              // 0..7
    const int m     = lane & 15;
    const int quad  = lane >> 4;

    const float* xrow = x + (size_t)(row0 + m) * DIMS_;

    // ---- hoisted A-load batch: 16 dwordx4 in flight before any consumer
    float4 a[2 * KPS];
    #pragma unroll
    for (int ks = 0; ks < KPS; ++ks) {
        const int kb = (slice * KPS + ks) * 32 + quad * 8;
        a[2 * ks + 0] = *reinterpret_cast<const float4*>(xrow + kb);
        a[2 * ks + 1] = *reinterpret_cast<const float4*>(xrow + kb + 4);
    }

    const short8* fv = reinterpret_cast<const short8*>(frag);
    f32x4 acc0 = {0.f, 0.f, 0.f, 0.f};
    f32x4 acc1 = {0.f, 0.f, 0.f, 0.f};

    #pragma unroll
    for (int ks = 0; ks < KPS; ++ks) {
        const int K0 = slice * KPS + ks;
        float f[8] = {a[2 * ks].x, a[2 * ks].y, a[2 * ks].z, a[2 * ks].w,
                      a[2 * ks + 1].x, a[2 * ks + 1].y, a[2 * ks + 1].z, a[2 * ks + 1].w};
        short8 ah, al;
        #pragma unroll
        for (int j = 0; j < 8; ++j) {
            unsigned short h = bf16_rne(f[j]);                // R5: rne hi
            float back = __uint_as_float(((unsigned int)h) << 16);
            ah[j] = (short)h;
            al[j] = (short)bf16_rne(f[j] - back);
        }
        short8 fh0 = fv[(K0 * 4 + 0) * 64 + lane];
        short8 fl0 = fv[(K0 * 4 + 1) * 64 + lane];
        short8 fh1 = fv[(K0 * 4 + 2) * 64 + lane];
        short8 fl1 = fv[(K0 * 4 + 3) * 64 + lane];
        acc0 = __builtin_amdgcn_mfma_f32_16x16x32_bf16(ah, fh0, acc0, 0, 0, 0);
        acc0 = __builtin_amdgcn_mfma_f32_16x16x32_bf16(al, fh0, acc0, 0, 0, 0);
        acc0 = __builtin_amdgcn_mfma_f32_16x16x32_bf16(ah, fl0, acc0, 0, 0, 0);
        acc1 = __builtin_amdgcn_mfma_f32_16x16x32_bf16(ah, fh1, acc1, 0, 0, 0);
        acc1 = __builtin_amdgcn_mfma_f32_16x16x32_bf16(al, fh1, acc1, 0, 0, 0);
        acc1 = __builtin_amdgcn_mfma_f32_16x16x32_bf16(ah, fl1, acc1, 0, 0, 0);
    }

    // C/D layout (verified m89): col = lane&15, row = (lane>>4)*4 + reg
    #pragma unroll
    for (int r = 0; r < 4; ++r) {
        int row = row0 + quad * 4 + r;
        float* p = part + ((size_t)slice * NROWS + row) * NCOL;
        p[m]      = acc0[r];
        p[m + 16] = acc1[r];
    }
}

// ---- k2: 8-slice reduction + epilogue (R5 exact)
__global__ __launch_bounds__(256)
void tgate_k2(const float* __restrict__ part,
              const float* __restrict__ b_cls,
              const float* __restrict__ b_sparse,
              const float* __restrict__ b_gates,
              const float* __restrict__ alpha,
              float* __restrict__ out)
{
    const int r = blockIdx.x * 256 + threadIdx.x;
    const float4* p4 = reinterpret_cast<const float4*>(part);

    float l[32];
    #pragma unroll
    for (int j = 0; j < 32; ++j) l[j] = 0.0f;
    #pragma unroll
    for (int s = 0; s < KSL; ++s) {
        size_t base = ((size_t)s * NROWS + r) * 8;
        #pragma unroll
        for (int q = 0; q < 8; ++q) {
            float4 v = p4[base + q];
            l[q * 4 + 0] += v.x; l[q * 4 + 1] += v.y;
            l[q * 4 + 2] += v.z; l[q * 4 + 3] += v.w;
        }
    }

    float lc[TT], lsp[TT], g[TT];
    #pragma unroll
    for (int t = 0; t < TT; ++t) {
        lc[t]  = l[t]      + b_cls[t];
        lsp[t] = l[10 + t] + b_sparse[t];
        float lg = l[20 + t] + b_gates[t];
        g[t] = 1.0f / (1.0f + __expf(-lg));
    }
    float m = lc[0];
    #pragma unroll
    for (int t = 1; t < TT; ++t) m = fmaxf(m, lc[t]);
    float esum = 0.0f, gdot = 0.0f;
    #pragma unroll
    for (int t = 0; t < TT; ++t) {
        float e = __expf(lc[t] - m);
        esum += e;
        gdot = fmaf(g[t], e, gdot);
    }
    float v1 = lsp[0], v2 = -1e30f, gv1 = g[0], gv2 = 0.0f;
    #pragma unroll
    for (int t = 1; t < TT; ++t) {
        if (lsp[t] > v1)      { v2 = v1; gv2 = gv1; v1 = lsp[t]; gv1 = g[t]; }
        else if (lsp[t] > v2) { v2 = lsp[t]; gv2 = g[t]; }
    }
    float s1 = 1.0f / (1.0f + __expf(v2 - v1));
    float s2 = 1.0f - s1;
    float a  = 1.0f / (1.0f + __expf(-alpha[0]));
    float sparse_dot = fmaf(gv1, s1, gv2 * s2);
    out[r] = fmaf(a, sparse_dot, (1.0f - a) * (gdot / esum));
}

extern "C" void kernel_launch(void* const* d_in, const int* in_sizes, int n_in,
                              void* d_out, int out_size, void* d_ws, size_t ws_size,
                              hipStream_t stream) {
    const float* x        = (const float*)d_in[0];
    const float* W_cls    = (const float*)d_in[1];
    const float* b_cls    = (const float*)d_in[2];
    const float* W_sparse = (const float*)d_in[3];
    const float* b_sparse = (const float*)d_in[4];
    const float* W_gates  = (const float*)d_in[5];
    const float* b_gates  = (const float*)d_in[6];
    const float* alpha    = (const float*)d_in[7];
    float* out = (float*)d_out;

    // ws carve: [0, 256KB) = B fragments; [512KB, +16.8MB) = partials
    unsigned short* frag = (unsigned short*)d_ws;
    float* part = (float*)((char*)d_ws + (512 << 10));

    tgate_k0<<<dim3(32), dim3(256), 0, stream>>>(W_cls, W_sparse, W_gates, frag);
    tgate_k1<<<dim3(NROWS / 64, KSL), dim3(256), 0, stream>>>(x, frag, part);
    tgate_k2<<<dim3(NROWS / 256), dim3(256), 0, stream>>>(part, b_cls, b_sparse,
                                                          b_gates, alpha, out);
}

// Round 8
// 230.143 us; speedup vs baseline: 1.0033x; 1.0033x over previous
//
#include <hip/hip_runtime.h>
#include <math.h>
#include <stdint.h>

// tgate_hybrid: B=4,S=4096,DIMS=2048,T=10,K=2.
// R8 = R7 bit-for-bit arithmetic (rne-hi split-bf16, KSL=8, same MFMA order,
// passed at absmax 0.00390625) + ONE mapping change: slice = (by+bx)&7.
// Rationale: x row stride 8 KB => HBM channel = f(col only); R7 dispatched
// all early blocks on slice 0 -> whole GPU camped on ~4 of ~32 channels
// (~2 TB/s ceiling, seen in ALL of R1-R7). Rotating slice by blockIdx.x
// spreads concurrent blocks across all 8 col-bands -> all channels active.
// Which block computes a (row,slice) pair changes; the FP sum itself is
// bit-identical, so output must be exactly 0.00390625 again.

#define NROWS   16384
#define DIMS_   2048
#define TT      10
#define NCOL    32
#define KSL     8                 // k-slices
#define KSTEPS  (DIMS_ / 32)      // 64 MFMA k-steps total
#define KPS     (KSTEPS / KSL)    // 8 k-steps per slice

typedef __attribute__((ext_vector_type(8))) short short8;
typedef __attribute__((ext_vector_type(4))) float f32x4;

__device__ __forceinline__ unsigned short bf16_rne(float f) {
    unsigned int u = __float_as_uint(f);
    unsigned int r = u + 0x7fffu + ((u >> 16) & 1u);
    return (unsigned short)(r >> 16);
}

// ---- k0: build B fragments. frag[(K0*4 + nt*2 + h)*64 + lane] = short8
//      B-frag layout (16x16x32): n = lane&15, k = (lane>>4)*8 + j.
__global__ __launch_bounds__(256)
void tgate_k0(const float* __restrict__ W_cls,
              const float* __restrict__ W_sparse,
              const float* __restrict__ W_gates,
              unsigned short* __restrict__ frag)
{
    int t = blockIdx.x * 256 + threadIdx.x;    // 8192 threads: (K0, nt, lane)
    int K0   = t >> 7;
    int nt   = (t >> 6) & 1;
    int lane = t & 63;
    int n  = nt * 16 + (lane & 15);
    int kb = K0 * 32 + (lane >> 4) * 8;
    short8 hi, lo;
    #pragma unroll
    for (int j = 0; j < 8; ++j) {
        int k = kb + j;
        float w = 0.0f;
        if (n < 10)      w = W_cls[k * TT + n];
        else if (n < 20) w = W_sparse[k * TT + n - 10];
        else if (n < 30) w = W_gates[k * TT + n - 20];
        unsigned short h = bf16_rne(w);
        float back = __uint_as_float(((unsigned int)h) << 16);
        hi[j] = (short)h;
        lo[j] = (short)bf16_rne(w - back);
    }
    short8* fv = reinterpret_cast<short8*>(frag);
    fv[(K0 * 4 + nt * 2 + 0) * 64 + lane] = hi;
    fv[(K0 * 4 + nt * 2 + 1) * 64 + lane] = lo;
}

// ---- k1: MFMA partial GEMM; R7 arithmetic, slice swizzled by blockIdx.x
__global__ __launch_bounds__(256)
void tgate_k1(const float* __restrict__ x,
              const unsigned short* __restrict__ frag,
              float* __restrict__ part)
{
    const int lane  = threadIdx.x & 63;
    const int wv    = threadIdx.x >> 6;
    const int bx    = blockIdx.x;                 // 0..255 row-group
    const int row0  = (bx * 4 + wv) * 16;
    const int slice = (blockIdx.y + bx) & 7;      // channel-decorrelating swizzle
    const int m     = lane & 15;
    const int quad  = lane >> 4;

    const float* xrow = x + (size_t)(row0 + m) * DIMS_;

    // ---- hoisted A-load batch: 16 dwordx4 in flight before any consumer
    float4 a[2 * KPS];
    #pragma unroll
    for (int ks = 0; ks < KPS; ++ks) {
        const int kb = (slice * KPS + ks) * 32 + quad * 8;
        a[2 * ks + 0] = *reinterpret_cast<const float4*>(xrow + kb);
        a[2 * ks + 1] = *reinterpret_cast<const float4*>(xrow + kb + 4);
    }

    const short8* fv = reinterpret_cast<const short8*>(frag);
    f32x4 acc0 = {0.f, 0.f, 0.f, 0.f};
    f32x4 acc1 = {0.f, 0.f, 0.f, 0.f};

    #pragma unroll
    for (int ks = 0; ks < KPS; ++ks) {
        const int K0 = slice * KPS + ks;
        float f[8] = {a[2 * ks].x, a[2 * ks].y, a[2 * ks].z, a[2 * ks].w,
                      a[2 * ks + 1].x, a[2 * ks + 1].y, a[2 * ks + 1].z, a[2 * ks + 1].w};
        short8 ah, al;
        #pragma unroll
        for (int j = 0; j < 8; ++j) {
            unsigned short h = bf16_rne(f[j]);                // rne hi (R5/R7 path)
            float back = __uint_as_float(((unsigned int)h) << 16);
            ah[j] = (short)h;
            al[j] = (short)bf16_rne(f[j] - back);
        }
        short8 fh0 = fv[(K0 * 4 + 0) * 64 + lane];
        short8 fl0 = fv[(K0 * 4 + 1) * 64 + lane];
        short8 fh1 = fv[(K0 * 4 + 2) * 64 + lane];
        short8 fl1 = fv[(K0 * 4 + 3) * 64 + lane];
        acc0 = __builtin_amdgcn_mfma_f32_16x16x32_bf16(ah, fh0, acc0, 0, 0, 0);
        acc0 = __builtin_amdgcn_mfma_f32_16x16x32_bf16(al, fh0, acc0, 0, 0, 0);
        acc0 = __builtin_amdgcn_mfma_f32_16x16x32_bf16(ah, fl0, acc0, 0, 0, 0);
        acc1 = __builtin_amdgcn_mfma_f32_16x16x32_bf16(ah, fh1, acc1, 0, 0, 0);
        acc1 = __builtin_amdgcn_mfma_f32_16x16x32_bf16(al, fh1, acc1, 0, 0, 0);
        acc1 = __builtin_amdgcn_mfma_f32_16x16x32_bf16(ah, fl1, acc1, 0, 0, 0);
    }

    // C/D layout (verified m89): col = lane&15, row = (lane>>4)*4 + reg
    #pragma unroll
    for (int r = 0; r < 4; ++r) {
        int row = row0 + quad * 4 + r;
        float* p = part + ((size_t)slice * NROWS + row) * NCOL;
        p[m]      = acc0[r];
        p[m + 16] = acc1[r];
    }
}

// ---- k2: 8-slice reduction + epilogue (R5/R7 exact)
__global__ __launch_bounds__(256)
void tgate_k2(const float* __restrict__ part,
              const float* __restrict__ b_cls,
              const float* __restrict__ b_sparse,
              const float* __restrict__ b_gates,
              const float* __restrict__ alpha,
              float* __restrict__ out)
{
    const int r = blockIdx.x * 256 + threadIdx.x;
    const float4* p4 = reinterpret_cast<const float4*>(part);

    float l[32];
    #pragma unroll
    for (int j = 0; j < 32; ++j) l[j] = 0.0f;
    #pragma unroll
    for (int s = 0; s < KSL; ++s) {
        size_t base = ((size_t)s * NROWS + r) * 8;
        #pragma unroll
        for (int q = 0; q < 8; ++q) {
            float4 v = p4[base + q];
            l[q * 4 + 0] += v.x; l[q * 4 + 1] += v.y;
            l[q * 4 + 2] += v.z; l[q * 4 + 3] += v.w;
        }
    }

    float lc[TT], lsp[TT], g[TT];
    #pragma unroll
    for (int t = 0; t < TT; ++t) {
        lc[t]  = l[t]      + b_cls[t];
        lsp[t] = l[10 + t] + b_sparse[t];
        float lg = l[20 + t] + b_gates[t];
        g[t] = 1.0f / (1.0f + __expf(-lg));
    }
    float m = lc[0];
    #pragma unroll
    for (int t = 1; t < TT; ++t) m = fmaxf(m, lc[t]);
    float esum = 0.0f, gdot = 0.0f;
    #pragma unroll
    for (int t = 0; t < TT; ++t) {
        float e = __expf(lc[t] - m);
        esum += e;
        gdot = fmaf(g[t], e, gdot);
    }
    float v1 = lsp[0], v2 = -1e30f, gv1 = g[0], gv2 = 0.0f;
    #pragma unroll
    for (int t = 1; t < TT; ++t) {
        if (lsp[t] > v1)      { v2 = v1; gv2 = gv1; v1 = lsp[t]; gv1 = g[t]; }
        else if (lsp[t] > v2) { v2 = lsp[t]; gv2 = g[t]; }
    }
    float s1 = 1.0f / (1.0f + __expf(v2 - v1));
    float s2 = 1.0f - s1;
    float a  = 1.0f / (1.0f + __expf(-alpha[0]));
    float sparse_dot = fmaf(gv1, s1, gv2 * s2);
    out[r] = fmaf(a, sparse_dot, (1.0f - a) * (gdot / esum));
}

extern "C" void kernel_launch(void* const* d_in, const int* in_sizes, int n_in,
                              void* d_out, int out_size, void* d_ws, size_t ws_size,
                              hipStream_t stream) {
    const float* x        = (const float*)d_in[0];
    const float* W_cls    = (const float*)d_in[1];
    const float* b_cls    = (const float*)d_in[2];
    const float* W_sparse = (const float*)d_in[3];
    const float* b_sparse = (const float*)d_in[4];
    const float* W_gates  = (const float*)d_in[5];
    const float* b_gates  = (const float*)d_in[6];
    const float* alpha    = (const float*)d_in[7];
    float* out = (float*)d_out;

    // ws carve: [0, 256KB) = B fragments; [512KB, +16.8MB) = partials
    unsigned short* frag = (unsigned short*)d_ws;
    float* part = (float*)((char*)d_ws + (512 << 10));

    tgate_k0<<<dim3(32), dim3(256), 0, stream>>>(W_cls, W_sparse, W_gates, frag);
    tgate_k1<<<dim3(NROWS / 64, KSL), dim3(256), 0, stream>>>(x, frag, part);
    tgate_k2<<<dim3(NROWS / 256), dim3(256), 0, stream>>>(part, b_cls, b_sparse,
                                                          b_gates, alpha, out);
}

// Round 9
// 219.414 us; speedup vs baseline: 1.0524x; 1.0489x over previous
//
#include <hip/hip_runtime.h>
#include <math.h>
#include <stdint.h>

// tgate_hybrid: B=4,S=4096,DIMS=2048,T=10,K=2.
// R9 = R8 bit-for-bit arithmetic (absmax must be exactly 0.00390625) with the
// A-operand path restructured for DRAM page locality: every global load
// instruction now reads 2 rows x 512 B CONTIGUOUS (vs 16 rows x 16 B at 8 KB
// power-of-2 stride in R1-R8 -> DRAM bank/row-buffer thrash, the ~2 TB/s
// ceiling seen in ALL rounds; BW scaled monotonically with per-row run length:
// 32B->1.2, 64B->1.5, 128B->2.1 TB/s). x staged via wave-private LDS chunks
// (16 rows x 128 cols fp32, pitch 132 = balanced banks, no barriers needed),
// MFMA fragments read from LDS; fp32 bits unchanged -> identical numerics.

#define NROWS   16384
#define DIMS_   2048
#define TT      10
#define NCOL    32
#define KSL     8                 // k-slices
#define KPS     8                 // k-steps per slice (KSL*KPS*32 = 2048)
#define PITCH   132               // LDS row pitch (floats): 16B-aligned, balanced banks

typedef __attribute__((ext_vector_type(8))) short short8;
typedef __attribute__((ext_vector_type(4))) float f32x4;

__device__ __forceinline__ unsigned short bf16_rne(float f) {
    unsigned int u = __float_as_uint(f);
    unsigned int r = u + 0x7fffu + ((u >> 16) & 1u);
    return (unsigned short)(r >> 16);
}

// ---- k0: build B fragments. frag[(K0*4 + nt*2 + h)*64 + lane] = short8
//      B-frag layout (16x16x32): n = lane&15, k = (lane>>4)*8 + j.
__global__ __launch_bounds__(256)
void tgate_k0(const float* __restrict__ W_cls,
              const float* __restrict__ W_sparse,
              const float* __restrict__ W_gates,
              unsigned short* __restrict__ frag)
{
    int t = blockIdx.x * 256 + threadIdx.x;    // 8192 threads: (K0, nt, lane)
    int K0   = t >> 7;
    int nt   = (t >> 6) & 1;
    int lane = t & 63;
    int n  = nt * 16 + (lane & 15);
    int kb = K0 * 32 + (lane >> 4) * 8;
    short8 hi, lo;
    #pragma unroll
    for (int j = 0; j < 8; ++j) {
        int k = kb + j;
        float w = 0.0f;
        if (n < 10)      w = W_cls[k * TT + n];
        else if (n < 20) w = W_sparse[k * TT + n - 10];
        else if (n < 30) w = W_gates[k * TT + n - 20];
        unsigned short h = bf16_rne(w);
        float back = __uint_as_float(((unsigned int)h) << 16);
        hi[j] = (short)h;
        lo[j] = (short)bf16_rne(w - back);
    }
    short8* fv = reinterpret_cast<short8*>(frag);
    fv[(K0 * 4 + nt * 2 + 0) * 64 + lane] = hi;
    fv[(K0 * 4 + nt * 2 + 1) * 64 + lane] = lo;
}

// ---- k1: MFMA partial GEMM; contiguous global loads -> wave-private LDS
__global__ __launch_bounds__(256)
void tgate_k1(const float* __restrict__ x,
              const unsigned short* __restrict__ frag,
              float* __restrict__ part)
{
    __shared__ float lds[4][16 * PITCH];   // 4 waves x 8448 B = 33792 B

    const int lane  = threadIdx.x & 63;
    const int wv    = __builtin_amdgcn_readfirstlane(threadIdx.x >> 6);
    const int bx    = blockIdx.x;
    const int row0  = (bx * 4 + wv) * 16;
    const int slice = (blockIdx.y + bx) & 7;   // keep R8 swizzle (neutral, safe)
    const int m     = lane & 15;
    const int quad  = lane >> 4;

    float* L = lds[wv];

    // staging mapping: instr t covers rows {2t, 2t+1} x 512 B contiguous each
    const int rs = lane >> 5;            // 0..1
    const int cs = (lane & 31) * 4;      // 0,4,..,124 (x4 floats per lane)

    const float4* x4 = reinterpret_cast<const float4*>(x);
    const int cb0 = slice * 256;         // chunk 0 col base (global)

    // ---- load chunk 0 (16 rows x 128 cols) : 8 contiguous 1-KB instructions
    float4 pre[8];
    #pragma unroll
    for (int t = 0; t < 8; ++t)
        pre[t] = x4[(size_t)(row0 + 2 * t + rs) * 512 + ((cb0 + cs) >> 2)];

    const short8* fv = reinterpret_cast<const short8*>(frag);
    f32x4 acc0 = {0.f, 0.f, 0.f, 0.f};
    f32x4 acc1 = {0.f, 0.f, 0.f, 0.f};

    #pragma unroll
    for (int ch = 0; ch < 2; ++ch) {
        // stage current chunk to LDS (wave-private; DS in-order => no barrier)
        #pragma unroll
        for (int t = 0; t < 8; ++t)
            *reinterpret_cast<float4*>(&L[(2 * t + rs) * PITCH + cs]) = pre[t];
        // prefetch next chunk while computing this one
        if (ch == 0) {
            #pragma unroll
            for (int t = 0; t < 8; ++t)
                pre[t] = x4[(size_t)(row0 + 2 * t + rs) * 512 + ((cb0 + 128 + cs) >> 2)];
        }
        #pragma unroll
        for (int ksl = 0; ksl < 4; ++ksl) {
            const int K0 = slice * KPS + ch * 4 + ksl;   // ascending, R8 order
            const float* src = &L[m * PITCH + ksl * 32 + quad * 8];
            float4 b0 = *reinterpret_cast<const float4*>(src);
            float4 b1 = *reinterpret_cast<const float4*>(src + 4);
            float f[8] = {b0.x, b0.y, b0.z, b0.w, b1.x, b1.y, b1.z, b1.w};
            short8 ah, al;
            #pragma unroll
            for (int j = 0; j < 8; ++j) {
                unsigned short h = bf16_rne(f[j]);               // rne hi (R5/R7/R8 path)
                float back = __uint_as_float(((unsigned int)h) << 16);
                ah[j] = (short)h;
                al[j] = (short)bf16_rne(f[j] - back);
            }
            short8 fh0 = fv[(K0 * 4 + 0) * 64 + lane];
            short8 fl0 = fv[(K0 * 4 + 1) * 64 + lane];
            short8 fh1 = fv[(K0 * 4 + 2) * 64 + lane];
            short8 fl1 = fv[(K0 * 4 + 3) * 64 + lane];
            acc0 = __builtin_amdgcn_mfma_f32_16x16x32_bf16(ah, fh0, acc0, 0, 0, 0);
            acc0 = __builtin_amdgcn_mfma_f32_16x16x32_bf16(al, fh0, acc0, 0, 0, 0);
            acc0 = __builtin_amdgcn_mfma_f32_16x16x32_bf16(ah, fl0, acc0, 0, 0, 0);
            acc1 = __builtin_amdgcn_mfma_f32_16x16x32_bf16(ah, fh1, acc1, 0, 0, 0);
            acc1 = __builtin_amdgcn_mfma_f32_16x16x32_bf16(al, fh1, acc1, 0, 0, 0);
            acc1 = __builtin_amdgcn_mfma_f32_16x16x32_bf16(ah, fl1, acc1, 0, 0, 0);
        }
    }

    // C/D layout (verified m89): col = lane&15, row = (lane>>4)*4 + reg
    #pragma unroll
    for (int r = 0; r < 4; ++r) {
        int row = row0 + quad * 4 + r;
        float* p = part + ((size_t)slice * NROWS + row) * NCOL;
        p[m]      = acc0[r];
        p[m + 16] = acc1[r];
    }
}

// ---- k2: 8-slice reduction + epilogue (R5/R7/R8 exact)
__global__ __launch_bounds__(256)
void tgate_k2(const float* __restrict__ part,
              const float* __restrict__ b_cls,
              const float* __restrict__ b_sparse,
              const float* __restrict__ b_gates,
              const float* __restrict__ alpha,
              float* __restrict__ out)
{
    const int r = blockIdx.x * 256 + threadIdx.x;
    const float4* p4 = reinterpret_cast<const float4*>(part);

    float l[32];
    #pragma unroll
    for (int j = 0; j < 32; ++j) l[j] = 0.0f;
    #pragma unroll
    for (int s = 0; s < KSL; ++s) {
        size_t base = ((size_t)s * NROWS + r) * 8;
        #pragma unroll
        for (int q = 0; q < 8; ++q) {
            float4 v = p4[base + q];
            l[q * 4 + 0] += v.x; l[q * 4 + 1] += v.y;
            l[q * 4 + 2] += v.z; l[q * 4 + 3] += v.w;
        }
    }

    float lc[TT], lsp[TT], g[TT];
    #pragma unroll
    for (int t = 0; t < TT; ++t) {
        lc[t]  = l[t]      + b_cls[t];
        lsp[t] = l[10 + t] + b_sparse[t];
        float lg = l[20 + t] + b_gates[t];
        g[t] = 1.0f / (1.0f + __expf(-lg));
    }
    float m = lc[0];
    #pragma unroll
    for (int t = 1; t < TT; ++t) m = fmaxf(m, lc[t]);
    float esum = 0.0f, gdot = 0.0f;
    #pragma unroll
    for (int t = 0; t < TT; ++t) {
        float e = __expf(lc[t] - m);
        esum += e;
        gdot = fmaf(g[t], e, gdot);
    }
    float v1 = lsp[0], v2 = -1e30f, gv1 = g[0], gv2 = 0.0f;
    #pragma unroll
    for (int t = 1; t < TT; ++t) {
        if (lsp[t] > v1)      { v2 = v1; gv2 = gv1; v1 = lsp[t]; gv1 = g[t]; }
        else if (lsp[t] > v2) { v2 = lsp[t]; gv2 = g[t]; }
    }
    float s1 = 1.0f / (1.0f + __expf(v2 - v1));
    float s2 = 1.0f - s1;
    float a  = 1.0f / (1.0f + __expf(-alpha[0]));
    float sparse_dot = fmaf(gv1, s1, gv2 * s2);
    out[r] = fmaf(a, sparse_dot, (1.0f - a) * (gdot / esum));
}

extern "C" void kernel_launch(void* const* d_in, const int* in_sizes, int n_in,
                              void* d_out, int out_size, void* d_ws, size_t ws_size,
                              hipStream_t stream) {
    const float* x        = (const float*)d_in[0];
    const float* W_cls    = (const float*)d_in[1];
    const float* b_cls    = (const float*)d_in[2];
    const float* W_sparse = (const float*)d_in[3];
    const float* b_sparse = (const float*)d_in[4];
    const float* W_gates  = (const float*)d_in[5];
    const float* b_gates  = (const float*)d_in[6];
    const float* alpha    = (const float*)d_in[7];
    float* out = (float*)d_out;

    // ws carve: [0, 256KB) = B fragments; [512KB, +16.8MB) = partials
    unsigned short* frag = (unsigned short*)d_ws;
    float* part = (float*)((char*)d_ws + (512 << 10));

    tgate_k0<<<dim3(32), dim3(256), 0, stream>>>(W_cls, W_sparse, W_gates, frag);
    tgate_k1<<<dim3(NROWS / 64, KSL), dim3(256), 0, stream>>>(x, frag, part);
    tgate_k2<<<dim3(NROWS / 256), dim3(256), 0, stream>>>(part, b_cls, b_sparse,
                                                          b_gates, alpha, out);
}

// Round 10
// 208.964 us; speedup vs baseline: 1.1050x; 1.0500x over previous
//
#include <hip/hip_runtime.h>
#include <math.h>
#include <stdint.h>

// tgate_hybrid: B=4,S=4096,DIMS=2048,T=10,K=2.
// R10 = R9 bit-identical per-(row,slice) arithmetic, restructured:
//  * wave owns a CONTIGUOUS 512-col span (2 slices, 4 chunks) -> 2 KB
//    DRAM runs per row (confirmed lever: BW monotone in run length).
//  * k2 fold+epilogue fused into k1: block = 16 rows x full K (4 waves x
//    2 slices), partials folded in LDS in ascending-s order (bit-identical
//    to k2's l=0; l+=part[s]) then identical epilogue in lanes 0..15.
//    Removes 33.6 MB partials round-trip + one launch.

#define NROWS   16384
#define DIMS_   2048
#define TT      10
#define PITCH   132               // LDS x-tile row pitch (floats)

typedef __attribute__((ext_vector_type(8))) short short8;
typedef __attribute__((ext_vector_type(4))) float f32x4;

__device__ __forceinline__ unsigned short bf16_rne(float f) {
    unsigned int u = __float_as_uint(f);
    unsigned int r = u + 0x7fffu + ((u >> 16) & 1u);
    return (unsigned short)(r >> 16);
}

// ---- k0: build B fragments (unchanged). frag[(K0*4 + nt*2 + h)*64 + lane]
//      B-frag layout (16x16x32): n = lane&15, k = (lane>>4)*8 + j.
__global__ __launch_bounds__(256)
void tgate_k0(const float* __restrict__ W_cls,
              const float* __restrict__ W_sparse,
              const float* __restrict__ W_gates,
              unsigned short* __restrict__ frag)
{
    int t = blockIdx.x * 256 + threadIdx.x;    // 8192 threads: (K0, nt, lane)
    int K0   = t >> 7;
    int nt   = (t >> 6) & 1;
    int lane = t & 63;
    int n  = nt * 16 + (lane & 15);
    int kb = K0 * 32 + (lane >> 4) * 8;
    short8 hi, lo;
    #pragma unroll
    for (int j = 0; j < 8; ++j) {
        int k = kb + j;
        float w = 0.0f;
        if (n < 10)      w = W_cls[k * TT + n];
        else if (n < 20) w = W_sparse[k * TT + n - 10];
        else if (n < 30) w = W_gates[k * TT + n - 20];
        unsigned short h = bf16_rne(w);
        float back = __uint_as_float(((unsigned int)h) << 16);
        hi[j] = (short)h;
        lo[j] = (short)bf16_rne(w - back);
    }
    short8* fv = reinterpret_cast<short8*>(frag);
    fv[(K0 * 4 + nt * 2 + 0) * 64 + lane] = hi;
    fv[(K0 * 4 + nt * 2 + 1) * 64 + lane] = lo;
}

// ---- k1: fused full-K MFMA GEMV + fold + epilogue
__global__ __launch_bounds__(256)
void tgate_k1(const float* __restrict__ x,
              const unsigned short* __restrict__ frag,
              const float* __restrict__ b_cls,
              const float* __restrict__ b_sparse,
              const float* __restrict__ b_gates,
              const float* __restrict__ alpha,
              float* __restrict__ out)
{
    __shared__ float lds[4][16 * PITCH];   // 33792 B; reused for fold scratch

    const int tid   = threadIdx.x;
    const int lane  = tid & 63;
    const int wv    = __builtin_amdgcn_readfirstlane(tid >> 6);
    const int row0  = blockIdx.x * 16;
    const int m     = lane & 15;
    const int quad  = lane >> 4;

    float* L = lds[wv];
    const int rs = lane >> 5;            // 0..1
    const int cs = (lane & 31) * 4;      // 0..124 (floats)
    const float4* x4 = reinterpret_cast<const float4*>(x);
    const int cb = wv * 512;             // wave's contiguous col base

    // chunk 0 load: 8 instrs, each 2 rows x 512 B contiguous
    float4 pre[8];
    #pragma unroll
    for (int t = 0; t < 8; ++t)
        pre[t] = x4[(size_t)(row0 + 2 * t + rs) * 512 + ((cb + cs) >> 2)];

    const short8* fv = reinterpret_cast<const short8*>(frag);
    f32x4 acc[2][2];
    #pragma unroll
    for (int h = 0; h < 2; ++h) {
        acc[h][0] = (f32x4){0.f, 0.f, 0.f, 0.f};
        acc[h][1] = (f32x4){0.f, 0.f, 0.f, 0.f};
    }

    #pragma unroll
    for (int c = 0; c < 4; ++c) {
        // stage chunk c (wave-private; DS in-order per wave => no barrier)
        #pragma unroll
        for (int t = 0; t < 8; ++t)
            *reinterpret_cast<float4*>(&L[(2 * t + rs) * PITCH + cs]) = pre[t];
        if (c < 3) {   // prefetch next contiguous 128-col chunk
            #pragma unroll
            for (int t = 0; t < 8; ++t)
                pre[t] = x4[(size_t)(row0 + 2 * t + rs) * 512
                            + ((cb + (c + 1) * 128 + cs) >> 2)];
        }
        const int h = c >> 1;                 // slice half: 0 or 1
        const int s = 2 * wv + h;             // global slice 0..7
        #pragma unroll
        for (int ksl = 0; ksl < 4; ++ksl) {
            const int K0 = s * 8 + (c & 1) * 4 + ksl;   // ascending per slice (R9 order)
            const float* src = &L[m * PITCH + ksl * 32 + quad * 8];
            float4 b0 = *reinterpret_cast<const float4*>(src);
            float4 b1 = *reinterpret_cast<const float4*>(src + 4);
            float f[8] = {b0.x, b0.y, b0.z, b0.w, b1.x, b1.y, b1.z, b1.w};
            short8 ah, al;
            #pragma unroll
            for (int j = 0; j < 8; ++j) {
                unsigned short hh = bf16_rne(f[j]);              // rne hi (R5..R9 path)
                float back = __uint_as_float(((unsigned int)hh) << 16);
                ah[j] = (short)hh;
                al[j] = (short)bf16_rne(f[j] - back);
            }
            short8 fh0 = fv[(K0 * 4 + 0) * 64 + lane];
            short8 fl0 = fv[(K0 * 4 + 1) * 64 + lane];
            short8 fh1 = fv[(K0 * 4 + 2) * 64 + lane];
            short8 fl1 = fv[(K0 * 4 + 3) * 64 + lane];
            acc[h][0] = __builtin_amdgcn_mfma_f32_16x16x32_bf16(ah, fh0, acc[h][0], 0, 0, 0);
            acc[h][0] = __builtin_amdgcn_mfma_f32_16x16x32_bf16(al, fh0, acc[h][0], 0, 0, 0);
            acc[h][0] = __builtin_amdgcn_mfma_f32_16x16x32_bf16(ah, fl0, acc[h][0], 0, 0, 0);
            acc[h][1] = __builtin_amdgcn_mfma_f32_16x16x32_bf16(ah, fh1, acc[h][1], 0, 0, 0);
            acc[h][1] = __builtin_amdgcn_mfma_f32_16x16x32_bf16(al, fh1, acc[h][1], 0, 0, 0);
            acc[h][1] = __builtin_amdgcn_mfma_f32_16x16x32_bf16(ah, fl1, acc[h][1], 0, 0, 0);
        }
    }

    // ---- partials to LDS: red[s][row][j], pitch 33  (16896 B, reuses lds)
    float* red = &lds[0][0];
    __syncthreads();                      // all tile reads done
    #pragma unroll
    for (int h = 0; h < 2; ++h) {
        int s = 2 * wv + h;
        #pragma unroll
        for (int r = 0; r < 4; ++r) {
            int row = quad * 4 + r;       // C/D layout (verified m89)
            red[(s * 16 + row) * 33 + m]      = acc[h][0][r];
            red[(s * 16 + row) * 33 + m + 16] = acc[h][1][r];
        }
    }
    __syncthreads();

    // ---- fold: bit-identical to k2 (l = 0; for s=0..7 ascending: l += part)
    float* fold = red + 8 * 16 * 33;      // disjoint scratch [16][33]
    #pragma unroll
    for (int u = 0; u < 2; ++u) {
        int i = tid * 2 + u;              // 0..511 = 16 rows x 32 cols
        int row = i >> 5, j = i & 31;
        float a = 0.0f;
        #pragma unroll
        for (int s = 0; s < 8; ++s) a += red[(s * 16 + row) * 33 + j];
        fold[row * 33 + j] = a;
    }
    __syncthreads();

    // ---- epilogue: lanes 0..15 of wave 0, one row each (k2 code verbatim)
    if (tid < 16) {
        const float* l = &fold[tid * 33];
        float lc[TT], lsp[TT], g[TT];
        #pragma unroll
        for (int t = 0; t < TT; ++t) {
            lc[t]  = l[t]      + b_cls[t];
            lsp[t] = l[10 + t] + b_sparse[t];
            float lg = l[20 + t] + b_gates[t];
            g[t] = 1.0f / (1.0f + __expf(-lg));
        }
        float mm = lc[0];
        #pragma unroll
        for (int t = 1; t < TT; ++t) mm = fmaxf(mm, lc[t]);
        float esum = 0.0f, gdot = 0.0f;
        #pragma unroll
        for (int t = 0; t < TT; ++t) {
            float e = __expf(lc[t] - mm);
            esum += e;
            gdot = fmaf(g[t], e, gdot);
        }
        float v1 = lsp[0], v2 = -1e30f, gv1 = g[0], gv2 = 0.0f;
        #pragma unroll
        for (int t = 1; t < TT; ++t) {
            if (lsp[t] > v1)      { v2 = v1; gv2 = gv1; v1 = lsp[t]; gv1 = g[t]; }
            else if (lsp[t] > v2) { v2 = lsp[t]; gv2 = g[t]; }
        }
        float s1 = 1.0f / (1.0f + __expf(v2 - v1));
        float s2 = 1.0f - s1;
        float a  = 1.0f / (1.0f + __expf(-alpha[0]));
        float sparse_dot = fmaf(gv1, s1, gv2 * s2);
        out[row0 + tid] = fmaf(a, sparse_dot, (1.0f - a) * (gdot / esum));
    }
}

extern "C" void kernel_launch(void* const* d_in, const int* in_sizes, int n_in,
                              void* d_out, int out_size, void* d_ws, size_t ws_size,
                              hipStream_t stream) {
    const float* x        = (const float*)d_in[0];
    const float* W_cls    = (const float*)d_in[1];
    const float* b_cls    = (const float*)d_in[2];
    const float* W_sparse = (const float*)d_in[3];
    const float* b_sparse = (const float*)d_in[4];
    const float* W_gates  = (const float*)d_in[5];
    const float* b_gates  = (const float*)d_in[6];
    const float* alpha    = (const float*)d_in[7];
    float* out = (float*)d_out;

    unsigned short* frag = (unsigned short*)d_ws;   // 256 KB

    tgate_k0<<<dim3(32), dim3(256), 0, stream>>>(W_cls, W_sparse, W_gates, frag);
    tgate_k1<<<dim3(NROWS / 16), dim3(256), 0, stream>>>(x, frag, b_cls, b_sparse,
                                                         b_gates, alpha, out);
}